// Round 6
// baseline (11171.839 us; speedup 1.0000x reference)
//
#include <hip/hip_runtime.h>
#include <math.h>

// MultilayerLSTM: B=16, S=512, D_IN=512, D_H=1024, D_OUT=2, VOCAB=32000
// Round 8: XCD-local layers, terminating-by-construction.
//   - Roles: XCD0 -> layer0 (64 blocks), XCD1 -> layer1 (64), any -> feeders
//     (256, 4 t-parity sets) computing xp1(t)=bf16(h0(t)@W1x+b1).
//   - xp1 PACKED into the second 8KB of the SAME (b,t) xp block (l0 reads the
//     full 16KB of block (b,t) only up to publishing f0>=t+1; feeder writes
//     (b,t) only after that flag). Footprint == round-3's proven 176MB.
//   - Producers dual-store h + flags: agent (MALL, correctness) then sc0
//     (local L2 copy, speed). Consumers: local poll capped 2048 iters ->
//     sticky agent fallback; all agent polls watchdog-capped -> 'broken'
//     (skip further waits; terminates instead of hanging).
//   - All waves hold 16 weight frags (~110 VGPR) -> launch_bounds(512,4)
//     -> 2 blocks/CU -> 64 blocks fill one XCD.

#define SLEN  512
#define HWREG_XCC_ID ((31 << 11) | (0 << 6) | 20)

#define C_CNT0 0
#define C_CNT1 1
#define C_CNTF 2
#define C_F0G  64
#define C_F0L  128
#define C_F1G  192
#define C_F1L  256
#define C_FF   512   // 256 entries

#define LOC_CAP 2048
#define WD_CAP  65536

typedef __attribute__((ext_vector_type(8))) short short8;
typedef __attribute__((ext_vector_type(4))) float f32x4;

__device__ inline unsigned short f2bfbits(float x) {
  union { float f; unsigned u; } v; v.f = x;
  unsigned r = v.u + 0x7FFF + ((v.u >> 16) & 1);  // RNE
  return (unsigned short)(r >> 16);
}

__device__ inline unsigned ld_sc0(const unsigned* p) {
  unsigned v;
  asm volatile("global_load_dword %0, %1, off sc0\n\ts_waitcnt vmcnt(0)"
               : "=v"(v) : "v"(p) : "memory");
  return v;
}
__device__ inline void st_sc0(unsigned* p, unsigned v) {
  asm volatile("global_store_dword %0, %1, off sc0" :: "v"(p), "v"(v) : "memory");
}
__device__ inline unsigned ld_ag(const unsigned* p) {
  return __hip_atomic_load(p, __ATOMIC_RELAXED, __HIP_MEMORY_SCOPE_AGENT);
}
__device__ inline void st_ag(unsigned* p, unsigned v) {
  __hip_atomic_store(p, v, __ATOMIC_RELAXED, __HIP_MEMORY_SCOPE_AGENT);
}
__device__ inline void cbar() { asm volatile("" ::: "memory"); }

// ---------------- zero control block ----------------
__global__ void zero_cnt_kernel(unsigned* cnt) {
  cnt[threadIdx.x] = 0;   // launched with 1024 threads
}

// ---------------- embedding gather ----------------
__global__ __launch_bounds__(256) void embed_kernel(const int* __restrict__ tokens,
                                                    const float* __restrict__ emb,
                                                    float* __restrict__ x0) {
  int idx = blockIdx.x * 256 + threadIdx.x;  // over 8192*128 float4s
  int r = idx >> 7, d4 = idx & 127;
  int tok = tokens[r];
  const float4* src = (const float4*)emb + (((size_t)tok) << 7) + d4;
  ((float4*)x0)[(((size_t)r) << 7) + d4] = *src;
}

// ---------------- xproj GEMM (layer 0 inputs) ----------------
__global__ __launch_bounds__(256) void xproj_kernel(
    const float* __restrict__ A, int K,
    const float* __restrict__ Wi, const float* __restrict__ Wf,
    const float* __restrict__ Wg, const float* __restrict__ Wo,
    const float* __restrict__ bi, const float* __restrict__ bf,
    const float* __restrict__ bg, const float* __restrict__ bo,
    float* __restrict__ Cout)
{
  __shared__ float As[8][128];
  __shared__ float Bs[8][128];
  const int tid = threadIdx.x;
  const int bn = blockIdx.x;
  const int bm = blockIdx.y;
  const int m0 = bm * 128;
  const int n0 = bn * 128;
  const int g = n0 >> 10;
  const float* W    = (g == 0) ? Wi : (g == 1) ? Wf : (g == 2) ? Wg : Wo;
  const float* bias = (g == 0) ? bi : (g == 1) ? bf : (g == 2) ? bg : bo;
  const int col0 = n0 & 1023;
  const int tx = tid & 15, ty = tid >> 4;
  const int lr = tid >> 1, lh = tid & 1;
  const int lk = tid >> 5, ln = (tid & 31) << 2;

  float acc[8][8];
#pragma unroll
  for (int i = 0; i < 8; ++i)
#pragma unroll
    for (int j = 0; j < 8; ++j) acc[i][j] = 0.f;

  for (int k0 = 0; k0 < K; k0 += 8) {
    float4 av = *(const float4*)(A + (size_t)(m0 + lr) * K + k0 + lh * 4);
    float4 bv = *(const float4*)(W + (size_t)(k0 + lk) * 1024 + col0 + ln);
    As[lh * 4 + 0][lr] = av.x;
    As[lh * 4 + 1][lr] = av.y;
    As[lh * 4 + 2][lr] = av.z;
    As[lh * 4 + 3][lr] = av.w;
    *(float4*)&Bs[lk][ln] = bv;
    __syncthreads();
#pragma unroll
    for (int p = 0; p < 8; ++p) {
      float a[8], b[8];
      *(float4*)&a[0] = *(const float4*)&As[p][ty * 8];
      *(float4*)&a[4] = *(const float4*)&As[p][ty * 8 + 4];
      *(float4*)&b[0] = *(const float4*)&Bs[p][tx * 4];
      *(float4*)&b[4] = *(const float4*)&Bs[p][64 + tx * 4];
#pragma unroll
      for (int i = 0; i < 8; ++i)
#pragma unroll
        for (int j = 0; j < 8; ++j) acc[i][j] += a[i] * b[j];
    }
    __syncthreads();
  }
  float4 bA = *(const float4*)(bias + col0 + tx * 4);
  float4 bB = *(const float4*)(bias + col0 + 64 + tx * 4);
#pragma unroll
  for (int i = 0; i < 8; ++i) {
    int m = m0 + ty * 8 + i;
    float* crow = Cout + (((size_t)m) << 12) + n0;
    float4 o1 = make_float4(acc[i][0] + bA.x, acc[i][1] + bA.y, acc[i][2] + bA.z, acc[i][3] + bA.w);
    float4 o2 = make_float4(acc[i][4] + bB.x, acc[i][5] + bB.y, acc[i][6] + bB.z, acc[i][7] + bB.w);
    *(float4*)(crow + tx * 4) = o1;
    *(float4*)(crow + 64 + tx * 4) = o2;
  }
}

// ---------------- fused XCD-local pipelined LSTM ----------------
__global__ __launch_bounds__(512, 4) void lstm_pipe(
    const float* xp,                 // no __restrict__: xp1 aliases its 2nd halves
    const float* __restrict__ W0i, const float* __restrict__ W0f,
    const float* __restrict__ W0g, const float* __restrict__ W0o,
    const float* __restrict__ W1i, const float* __restrict__ W1f,
    const float* __restrict__ W1g, const float* __restrict__ W1o,
    const float* __restrict__ b1i, const float* __restrict__ b1f,
    const float* __restrict__ b1g, const float* __restrict__ b1o,
    const float* __restrict__ Wfc,
    short* __restrict__ h0,
    short* __restrict__ h1,
    unsigned short* xp1,             // bf16; = (ushort*)xp, 2nd 8KB of each (b,t) block
    float2* __restrict__ part,
    unsigned* __restrict__ ctl)
{
  __shared__ float Pre[8][16][17];
  __shared__ int s_role;
  const int tid  = threadIdx.x;
  const int wv   = tid >> 6;
  const int g    = wv & 3;           // gate
  const int kh   = wv >> 2;          // K-half
  const int lane = tid & 63;
  const int q    = lane >> 4;
  const int n    = lane & 15;
  const int cb   = tid >> 4, cc = tid & 15;  // cell mapping (tid<256)

  unsigned* f0G = ctl + C_F0G;
  unsigned* f0L = ctl + C_F0L;
  unsigned* f1G = ctl + C_F1G;
  unsigned* f1L = ctl + C_F1L;
  unsigned* fF  = ctl + C_FF;

  // ---------- role claim (terminating) ----------
  if (tid == 0) {
    unsigned xid = (unsigned)__builtin_amdgcn_s_getreg(HWREG_XCC_ID) & 0xFu;
    int role = -1;
    unsigned tk;
    if (xid == 0u)      { tk = atomicAdd(&ctl[C_CNT0], 1u); if (tk < 64u) role = (int)tk; }
    else if (xid == 1u) { tk = atomicAdd(&ctl[C_CNT1], 1u); if (tk < 64u) role = 64 + (int)tk; }
    if (role < 0) { tk = atomicAdd(&ctl[C_CNTF], 1u); if (tk < 256u) role = 128 + (int)tk; }
    if (role < 0) {
      // capped wait for layer pools to fill, then force-claim leftovers
      int w = 0;
      for (;;) {
        if (ld_ag(&ctl[C_CNT0]) >= 64u && ld_ag(&ctl[C_CNT1]) >= 64u) break;
        if (++w > 4096) break;
        __builtin_amdgcn_s_sleep(8);
      }
      if (ld_ag(&ctl[C_CNT0]) < 64u) { tk = atomicAdd(&ctl[C_CNT0], 1u); if (tk < 64u) role = (int)tk; }
      if (role < 0 && ld_ag(&ctl[C_CNT1]) < 64u) { tk = atomicAdd(&ctl[C_CNT1], 1u); if (tk < 64u) role = 64 + (int)tk; }
    }
    s_role = role;
  }
  __syncthreads();
  const int role = s_role;
  if (role < 0) return;

  int use_loc = 1, broken = 0;

  if (role < 64) {
    // ================= layer 0 recurrence (XCD0-local) =================
    const int rr = role, c0 = rr << 4;
    const float* Wsel = (g == 0) ? W0i : (g == 1) ? W0f : (g == 2) ? W0g : W0o;
    short8 wfrag[16];
#pragma unroll
    for (int kk = 0; kk < 16; ++kk)
#pragma unroll
      for (int j = 0; j < 8; ++j)
        wfrag[kk][j] = (short)f2bfbits(
            Wsel[(size_t)(512 + kh * 512 + kk * 32 + q * 8 + j) * 1024 + c0 + n]);

    float Creg = 0.f;
    const float* xpb = xp + ((size_t)g << 10) + c0 + n;
    f32x4 xpn = {0.f, 0.f, 0.f, 0.f};
    if (kh == 0) {
#pragma unroll
      for (int r = 0; r < 4; ++r)
        xpn[r] = xpb[((size_t)((q * 4 + r) * SLEN)) << 12];
    }

    for (int t = 0; t < SLEN; ++t) {
      if (t > 0 && !broken) {
        const unsigned tgt = (unsigned)t;
        if (use_loc) {
          int it = 0;
          for (;;) { unsigned v = ld_sc0(&f0L[lane]); if (__all((int)(v >= tgt))) break;
                     if (++it > LOC_CAP) { use_loc = 0; break; } __builtin_amdgcn_s_sleep(1); }
        }
        if (!use_loc) {
          int it = 0;
          for (;;) { unsigned v = ld_ag(&f0G[lane]); if (__all((int)(v >= tgt))) break;
                     if (++it > WD_CAP) { broken = 1; break; } __builtin_amdgcn_s_sleep(1); }
        }
        cbar();
      }
      f32x4 acc = (kh == 0) ? xpn : f32x4{0.f, 0.f, 0.f, 0.f};
      f32x4 acc2 = {0.f, 0.f, 0.f, 0.f};
      if (kh == 0 && t + 1 < SLEN) {   // prefetch next xp row (hidden under MFMAs)
#pragma unroll
        for (int r = 0; r < 4; ++r)
          xpn[r] = xpb[((size_t)((q * 4 + r) * SLEN + t + 1)) << 12];
      }
      if (t > 0) {
        const short* hrow = h0 + (((size_t)(t - 1)) << 14) + n * 1024 + kh * 512 + q * 8;
#pragma unroll
        for (int kk = 0; kk < 16; kk += 2) {
          short8 a0 = *(const short8*)(hrow + kk * 32);
          short8 a1 = *(const short8*)(hrow + kk * 32 + 32);
          acc  = __builtin_amdgcn_mfma_f32_16x16x32_bf16(a0, wfrag[kk],     acc,  0, 0, 0);
          acc2 = __builtin_amdgcn_mfma_f32_16x16x32_bf16(a1, wfrag[kk + 1], acc2, 0, 0, 0);
        }
#pragma unroll
        for (int r = 0; r < 4; ++r) acc[r] += acc2[r];
      }
#pragma unroll
      for (int r = 0; r < 4; ++r) Pre[wv][q * 4 + r][n] = acc[r];
      __syncthreads();

      if (tid < 256) {
        float pI = Pre[0][cb][cc] + Pre[4][cb][cc];
        float pF = Pre[1][cb][cc] + Pre[5][cb][cc];
        float pG = Pre[2][cb][cc] + Pre[6][cb][cc];
        float pO = Pre[3][cb][cc] + Pre[7][cb][cc];
        float gI = 1.f / (1.f + __expf(-pI));
        float gF = 1.f / (1.f + __expf(-pF));
        float gG = tanhf(pG);
        float gO = 1.f / (1.f + __expf(-pO));
        Creg = gF * Creg + gI * gG;
        float h = gO * tanhf(Creg);

        unsigned mybits = (unsigned)f2bfbits(h);
        unsigned nbbits = (unsigned)__shfl_xor((int)mybits, 1, 64);
        if ((cc & 1) == 0) {
          unsigned pk = mybits | (nbbits << 16);
          unsigned* addr = (unsigned*)(h0 + (((size_t)(t * 16 + cb)) << 10) + c0 + cc);
          st_ag(addr, pk);    // MALL copy (correctness; proven path)
          st_sc0(addr, pk);   // local L2 copy (speed), same value
        }
      }
      asm volatile("s_waitcnt vmcnt(0)" ::: "memory");
      __syncthreads();        // all h stores drained block-wide
      if (tid == 0) {
        st_ag(&f0G[rr], (unsigned)(t + 1));
        st_sc0(&f0L[rr], (unsigned)(t + 1));
      }
    }
  } else if (role < 128) {
    // ================= layer 1 recurrence (XCD1-local, K=1024) =================
    const int rr = role - 64, c0 = rr << 4;
    const float* Wsel = (g == 0) ? W1i : (g == 1) ? W1f : (g == 2) ? W1g : W1o;
    short8 wfrag[16];  // recurrent rows 1024 + kh*512 ..
#pragma unroll
    for (int kk = 0; kk < 16; ++kk)
#pragma unroll
      for (int j = 0; j < 8; ++j)
        wfrag[kk][j] = (short)f2bfbits(
            Wsel[(size_t)(1024 + kh * 512 + kk * 32 + q * 8 + j) * 1024 + c0 + n]);
    const float wfc0 = Wfc[(c0 + cc) * 2 + 0];
    const float wfc1 = Wfc[(c0 + cc) * 2 + 1];
    float Creg = 0.f;

    for (int t = 0; t < SLEN; ++t) {
      if (!broken) {  // xp1(t) ready: feeder parity set (t&3) done step t
        const unsigned tgtF = (unsigned)(t >> 2) + 1u;
        const unsigned base = ((unsigned)t & 3u) * 64u;
        int it = 0;
        for (;;) { unsigned v = ld_ag(&fF[base + lane]); if (__all((int)(v >= tgtF))) break;
                   if (++it > WD_CAP) { broken = 1; break; } __builtin_amdgcn_s_sleep(1); }
        cbar();
      }
      if (t > 0 && !broken) {
        const unsigned tgt = (unsigned)t;
        if (use_loc) {
          int it = 0;
          for (;;) { unsigned v = ld_sc0(&f1L[lane]); if (__all((int)(v >= tgt))) break;
                     if (++it > LOC_CAP) { use_loc = 0; break; } __builtin_amdgcn_s_sleep(1); }
        }
        if (!use_loc) {
          int it = 0;
          for (;;) { unsigned v = ld_ag(&f1G[lane]); if (__all((int)(v >= tgt))) break;
                     if (++it > WD_CAP) { broken = 1; break; } __builtin_amdgcn_s_sleep(1); }
        }
        cbar();
      }

      f32x4 acc = {0.f, 0.f, 0.f, 0.f};
      f32x4 acc2 = {0.f, 0.f, 0.f, 0.f};
      if (kh == 0) {  // xp1(t): bf16 -> f32 acc init (bias folded by feeders)
#pragma unroll
        for (int r = 0; r < 4; ++r) {
          unsigned u = (unsigned)xp1[(((size_t)((q * 4 + r) * SLEN + t)) << 13) + 4096 + (g << 10) + c0 + n] << 16;
          acc[r] = __uint_as_float(u);
        }
      }
      if (t > 0) {
        const short* hrow = h1 + (((size_t)(t - 1)) << 14) + n * 1024 + kh * 512 + q * 8;
#pragma unroll
        for (int kk = 0; kk < 16; kk += 2) {
          short8 a0 = *(const short8*)(hrow + kk * 32);
          short8 a1 = *(const short8*)(hrow + kk * 32 + 32);
          acc  = __builtin_amdgcn_mfma_f32_16x16x32_bf16(a0, wfrag[kk],     acc,  0, 0, 0);
          acc2 = __builtin_amdgcn_mfma_f32_16x16x32_bf16(a1, wfrag[kk + 1], acc2, 0, 0, 0);
        }
#pragma unroll
        for (int r = 0; r < 4; ++r) acc[r] += acc2[r];
      }
#pragma unroll
      for (int r = 0; r < 4; ++r) Pre[wv][q * 4 + r][n] = acc[r];
      __syncthreads();

      if (tid < 256) {
        float pI = Pre[0][cb][cc] + Pre[4][cb][cc];
        float pF = Pre[1][cb][cc] + Pre[5][cb][cc];
        float pG = Pre[2][cb][cc] + Pre[6][cb][cc];
        float pO = Pre[3][cb][cc] + Pre[7][cb][cc];
        float gI = 1.f / (1.f + __expf(-pI));
        float gF = 1.f / (1.f + __expf(-pF));
        float gG = tanhf(pG);
        float gO = 1.f / (1.f + __expf(-pO));
        Creg = gF * Creg + gI * gG;
        float h = gO * tanhf(Creg);

        float p0 = h * wfc0, p1 = h * wfc1;
#pragma unroll
        for (int m = 1; m < 16; m <<= 1) {
          p0 += __shfl_xor(p0, m, 64);
          p1 += __shfl_xor(p1, m, 64);
        }
        if (cc == 0)
          part[(size_t)(cb * SLEN + t) * 64 + rr] = make_float2(p0, p1);

        unsigned mybits = (unsigned)f2bfbits(h);
        unsigned nbbits = (unsigned)__shfl_xor((int)mybits, 1, 64);
        if ((cc & 1) == 0) {
          unsigned pk = mybits | (nbbits << 16);
          unsigned* addr = (unsigned*)(h1 + (((size_t)(t * 16 + cb)) << 10) + c0 + cc);
          st_ag(addr, pk);
          st_sc0(addr, pk);
        }
      }
      asm volatile("s_waitcnt vmcnt(0)" ::: "memory");
      __syncthreads();
      if (tid == 0) {
        st_ag(&f1G[rr], (unsigned)(t + 1));
        st_sc0(&f1L[rr], (unsigned)(t + 1));
      }
    }
  } else {
    // ================= feeders: xp1(t) = h0(t) @ W1x + b1 (4 parity sets) =====
    const int f = role - 128;        // 0..255
    const int par = f >> 6;          // t mod 4
    const int c0f = (f & 63) << 4;
    const float* Wsel = (g == 0) ? W1i : (g == 1) ? W1f : (g == 2) ? W1g : W1o;
    short8 wfrag[16];  // input rows 0..1023 (kh half)
#pragma unroll
    for (int kk = 0; kk < 16; ++kk)
#pragma unroll
      for (int j = 0; j < 8; ++j)
        wfrag[kk][j] = (short)f2bfbits(
            Wsel[(size_t)(kh * 512 + kk * 32 + q * 8 + j) * 1024 + c0f + n]);
    float bias4[4] = {0.f, 0.f, 0.f, 0.f};
    if (tid < 256) {
      bias4[0] = b1i[c0f + cc]; bias4[1] = b1f[c0f + cc];
      bias4[2] = b1g[c0f + cc]; bias4[3] = b1o[c0f + cc];
    }

    for (int t = par; t < SLEN; t += 4) {
      if (!broken) {
        const unsigned tgt = (unsigned)(t + 1);
        int it = 0;
        for (;;) { unsigned v = ld_ag(&f0G[lane]); if (__all((int)(v >= tgt))) break;
                   if (++it > WD_CAP) { broken = 1; break; } __builtin_amdgcn_s_sleep(2); }
        cbar();
      }
      const short* xrow = h0 + (((size_t)t) << 14) + n * 1024 + kh * 512 + q * 8;
      f32x4 acc = {0.f, 0.f, 0.f, 0.f};
      f32x4 acc2 = {0.f, 0.f, 0.f, 0.f};
#pragma unroll
      for (int kk = 0; kk < 16; kk += 2) {
        short8 a0 = *(const short8*)(xrow + kk * 32);
        short8 a1 = *(const short8*)(xrow + kk * 32 + 32);
        acc  = __builtin_amdgcn_mfma_f32_16x16x32_bf16(a0, wfrag[kk],     acc,  0, 0, 0);
        acc2 = __builtin_amdgcn_mfma_f32_16x16x32_bf16(a1, wfrag[kk + 1], acc2, 0, 0, 0);
      }
#pragma unroll
      for (int r = 0; r < 4; ++r) acc[r] += acc2[r];
#pragma unroll
      for (int r = 0; r < 4; ++r) Pre[wv][q * 4 + r][n] = acc[r];
      __syncthreads();

      if (tid < 256) {
#pragma unroll
        for (int g2 = 0; g2 < 4; ++g2) {
          float pv = Pre[g2][cb][cc] + Pre[g2 + 4][cb][cc] + bias4[g2];
          unsigned my = (unsigned)f2bfbits(pv);
          unsigned nb = (unsigned)__shfl_xor((int)my, 1, 64);
          if ((cc & 1) == 0) {
            unsigned pk = my | (nb << 16);
            st_ag((unsigned*)(xp1 + (((size_t)(cb * SLEN + t)) << 13) + 4096 + (g2 << 10) + c0f + cc), pk);
          }
        }
      }
      asm volatile("s_waitcnt vmcnt(0)" ::: "memory");
      __syncthreads();
      if (tid == 0) st_ag(&fF[f], (unsigned)(t >> 2) + 1u);
    }
  }
}

// ---------------- finalize: 64-way partial sum + bias + log_softmax ----------------
__global__ __launch_bounds__(256) void finalize_kernel(const float2* __restrict__ part,
                                                       const float* __restrict__ bfc,
                                                       float* __restrict__ out)
{
  const int lane = threadIdx.x & 63;
  const int row = blockIdx.x * 4 + (threadIdx.x >> 6);
  float2 v = part[(size_t)row * 64 + lane];
  float s0 = v.x, s1 = v.y;
#pragma unroll
  for (int off = 32; off > 0; off >>= 1) {
    s0 += __shfl_down(s0, off);
    s1 += __shfl_down(s1, off);
  }
  if (lane == 0) {
    s0 += bfc[0];
    s1 += bfc[1];
    float m = fmaxf(s0, s1);
    float lse = m + logf(expf(s0 - m) + expf(s1 - m));
    out[((size_t)row << 1) + 0] = s0 - lse;
    out[((size_t)row << 1) + 1] = s1 - lse;
  }
}

extern "C" void kernel_launch(void* const* d_in, const int* in_sizes, int n_in,
                              void* d_out, int out_size, void* d_ws, size_t ws_size,
                              hipStream_t stream)
{
  const int*   tokens = (const int*)d_in[0];
  const float* emb = (const float*)d_in[1];
  const float* W0i = (const float*)d_in[2];
  const float* b0i = (const float*)d_in[3];
  const float* W0f = (const float*)d_in[4];
  const float* b0f = (const float*)d_in[5];
  const float* W0g = (const float*)d_in[6];
  const float* b0g = (const float*)d_in[7];
  const float* W0o = (const float*)d_in[8];
  const float* b0o = (const float*)d_in[9];
  const float* W1i = (const float*)d_in[10];
  const float* b1i = (const float*)d_in[11];
  const float* W1f = (const float*)d_in[12];
  const float* b1f = (const float*)d_in[13];
  const float* W1g = (const float*)d_in[14];
  const float* b1g = (const float*)d_in[15];
  const float* W1o = (const float*)d_in[16];
  const float* b1o = (const float*)d_in[17];
  const float* Wfc = (const float*)d_in[18];
  const float* bfc = (const float*)d_in[19];
  float* out = (float*)d_out;

  float* ws = (float*)d_ws;
  float* x0 = ws;                               // 16MB embed out; aliased h0 (bf16)
  float* hA = x0 + (size_t)8192 * 512;          // 32MB: h1 (16MB) + part (4MB)
  float* xp = hA + (size_t)8192 * 1024;         // 128MB l0 x-preacts (f32); 2nd 8KB
                                                // of each (b,t) block reused as xp1
  unsigned* ctl = (unsigned*)(xp + (size_t)8192 * 4096);  // 1024 u32 (proven offset)

  short*  h0   = (short*)x0;                    // bf16 [t][b][1024]
  short*  h1   = (short*)hA;                    // bf16 [t][b][1024]
  float2* part = (float2*)(hA + (size_t)8192 * 512);
  unsigned short* xp1 = (unsigned short*)xp;    // bf16, packed in-place

  zero_cnt_kernel<<<1, 1024, 0, stream>>>(ctl);
  embed_kernel<<<4096, 256, 0, stream>>>(tokens, emb, x0);
  xproj_kernel<<<dim3(32, 64), 256, 0, stream>>>(x0, 512, W0i, W0f, W0g, W0o,
                                                 b0i, b0f, b0g, b0o, xp);
  lstm_pipe<<<1024, 512, 0, stream>>>(xp,
                                      W0i, W0f, W0g, W0o,
                                      W1i, W1f, W1g, W1o,
                                      b1i, b1f, b1g, b1o,
                                      Wfc, h0, h1, xp1, part, ctl);
  finalize_kernel<<<2048, 256, 0, stream>>>(part, bfc, out);
}

// Round 7
// 5625.966 us; speedup vs baseline: 1.9858x; 1.9858x over previous
//
#include <hip/hip_runtime.h>
#include <math.h>

// MultilayerLSTM: B=16, S=512, D_IN=512, D_H=1024, D_OUT=2, VOCAB=32000
// Round 9: revert to the verified round-3 recurrence (5850us total) and bank
// safe gains. XCD-local line abandoned (round-6: dual-store tripled writes,
// feeders+polls regressed to 9.6ms).
//   - xproj is now MFMA bf16 (exact recurrence frag pattern): embed emits bf16
//     x0; wconv transposes W0 input rows to Wt[col][k] bf16 (placed in the hA
//     region's 12MB spare -> footprint unchanged); ~500us VALU GEMM -> ~80us.
//   - lstm_pipe == round-3 verified code except: (a) l1 waves poll their OWN
//     dependency only (kh=0: f0>=t+1, kh=1: f1>=t) so the recurrent half runs
//     under the f0 wait; (b) l0 publishes f0 to two arrays (f0a own / f0b l1)
//     to de-share hot flag lines; (c) xp prefetch issued before the poll.

#define SLEN  512

#define C_F0A  64
#define C_F0B  128
#define C_F1   192

typedef __attribute__((ext_vector_type(8))) short short8;
typedef __attribute__((ext_vector_type(4))) float f32x4;

__device__ inline unsigned short f2bfbits(float x) {
  union { float f; unsigned u; } v; v.f = x;
  unsigned r = v.u + 0x7FFF + ((v.u >> 16) & 1);  // RNE
  return (unsigned short)(r >> 16);
}

__device__ inline unsigned ld_ag(const unsigned* p) {
  return __hip_atomic_load(p, __ATOMIC_RELAXED, __HIP_MEMORY_SCOPE_AGENT);
}
__device__ inline void st_ag(unsigned* p, unsigned v) {
  __hip_atomic_store(p, v, __ATOMIC_RELAXED, __HIP_MEMORY_SCOPE_AGENT);
}

// ---------------- zero flags ----------------
__global__ void zero_cnt_kernel(unsigned* cnt) {
  cnt[threadIdx.x] = 0;   // launched with 256 threads
}

// ---------------- embedding gather -> bf16 x0 ----------------
__global__ __launch_bounds__(256) void embed_bf16_kernel(const int* __restrict__ tokens,
                                                         const float* __restrict__ emb,
                                                         short* __restrict__ x0bf) {
  int idx = blockIdx.x * 256 + threadIdx.x;   // over 8192 * 64 chunks of 8
  int r = idx >> 6, c8 = (idx & 63) << 3;
  int tok = tokens[r];
  const float* src = emb + ((size_t)tok << 9) + c8;
  float4 a = *(const float4*)(src);
  float4 b = *(const float4*)(src + 4);
  short8 o;
  o[0] = (short)f2bfbits(a.x); o[1] = (short)f2bfbits(a.y);
  o[2] = (short)f2bfbits(a.z); o[3] = (short)f2bfbits(a.w);
  o[4] = (short)f2bfbits(b.x); o[5] = (short)f2bfbits(b.y);
  o[6] = (short)f2bfbits(b.z); o[7] = (short)f2bfbits(b.w);
  *(short8*)(x0bf + ((size_t)r << 9) + c8) = o;
}

// ---------------- W0 input rows -> transposed bf16 Wt[gate*1024+col][512] ----------------
__global__ __launch_bounds__(256) void wconv_kernel(const float* __restrict__ Wi,
                                                    const float* __restrict__ Wf,
                                                    const float* __restrict__ Wg,
                                                    const float* __restrict__ Wo,
                                                    short* __restrict__ Wt) {
  int gid = blockIdx.x * 256 + threadIdx.x;   // 4 * 1024 * 64
  int gi = gid >> 16;
  int rem = gid & 65535;
  int col = rem >> 6;
  int k8 = (rem & 63) << 3;
  const float* W = (gi == 0) ? Wi : (gi == 1) ? Wf : (gi == 2) ? Wg : Wo;
  short8 o;
#pragma unroll
  for (int j = 0; j < 8; ++j)
    o[j] = (short)f2bfbits(W[(size_t)(k8 + j) * 1024 + col]);
  *(short8*)(Wt + (((size_t)((gi << 10) + col)) << 9) + k8) = o;
}

// ---------------- xproj via MFMA: xp[m][4096] = x0bf[m][512] @ W + b ----------------
// grid (64, 512): x = (gate<<4 | coltile), y = m-tile (16 rows, same batch).
// Exact recurrence frag pattern: A row n stride 512, B from Wt[col][k].
__global__ __launch_bounds__(256) void xproj_mfma_kernel(
    const short* __restrict__ x0bf,
    const short* __restrict__ Wt,
    const float* __restrict__ bi, const float* __restrict__ bf,
    const float* __restrict__ bg, const float* __restrict__ bo,
    float* __restrict__ xp)
{
  const int tid = threadIdx.x;
  const int w = tid >> 6;
  const int lane = tid & 63;
  const int q = lane >> 4;
  const int n = lane & 15;
  const int cx = blockIdx.x;
  const int g = cx >> 4;
  const int cbase = ((cx & 15) << 6) + (w << 4);   // col within gate
  const int m0 = blockIdx.y << 4;
  const float* bias = (g == 0) ? bi : (g == 1) ? bf : (g == 2) ? bg : bo;

  // 16 B-frags: Wt[(g<<10)+cbase+n][kk*32 + q*8 ..]
  const short* wp = Wt + (((size_t)((g << 10) + cbase + n)) << 9) + q * 8;
  short8 wfrag[16];
#pragma unroll
  for (int kk = 0; kk < 16; ++kk) wfrag[kk] = *(const short8*)(wp + kk * 32);

  const float bcol = bias[cbase + n];
  f32x4 acc, acc2 = {0.f, 0.f, 0.f, 0.f};
#pragma unroll
  for (int r = 0; r < 4; ++r) acc[r] = bcol;

  const short* ap = x0bf + (((size_t)(m0 + n)) << 9) + q * 8;
#pragma unroll
  for (int kk = 0; kk < 16; kk += 2) {
    short8 a0 = *(const short8*)(ap + kk * 32);
    short8 a1 = *(const short8*)(ap + kk * 32 + 32);
    acc  = __builtin_amdgcn_mfma_f32_16x16x32_bf16(a0, wfrag[kk],     acc,  0, 0, 0);
    acc2 = __builtin_amdgcn_mfma_f32_16x16x32_bf16(a1, wfrag[kk + 1], acc2, 0, 0, 0);
  }
#pragma unroll
  for (int r = 0; r < 4; ++r) acc[r] += acc2[r];

#pragma unroll
  for (int r = 0; r < 4; ++r)
    xp[(((size_t)(m0 + q * 4 + r)) << 12) + (g << 10) + cbase + n] = acc[r];
}

// ---------------- fused pipelined 2-layer LSTM recurrence (round-3 verified) ----------------
// 128 blocks x 512 threads (8 waves). Wave wv: gate = wv&3, K-half = wv>>2.
// blk 0..63: layer 0 cols blk*16 (K=1024 recurrent, halves of 512).
// blk 64..127: layer 1 cols (blk-64)*16 (K=2048: half0 = h0(t), half1 = h1(t-1)).
__global__ __launch_bounds__(512, 2) void lstm_pipe(
    const float* __restrict__ xp,
    const float* __restrict__ W0i, const float* __restrict__ W0f,
    const float* __restrict__ W0g, const float* __restrict__ W0o,
    const float* __restrict__ W1i, const float* __restrict__ W1f,
    const float* __restrict__ W1g, const float* __restrict__ W1o,
    const float* __restrict__ b1i, const float* __restrict__ b1f,
    const float* __restrict__ b1g, const float* __restrict__ b1o,
    const float* __restrict__ Wfc,
    short* __restrict__ h0b16,
    short* __restrict__ h1b16,
    float2* __restrict__ part,
    unsigned* __restrict__ ctl)
{
  __shared__ float Pre[8][16][17];
  const int tid  = threadIdx.x;
  const int wv   = tid >> 6;         // 0..7
  const int g    = wv & 3;           // gate
  const int kh   = wv >> 2;          // K-half
  const int lane = tid & 63;
  const int q    = lane >> 4;
  const int n    = lane & 15;
  const int cb   = tid >> 4, cc = tid & 15;  // cell mapping (tid<256)

  unsigned* f0a = ctl + C_F0A;
  unsigned* f0b = ctl + C_F0B;
  unsigned* f1  = ctl + C_F1;

  if (blockIdx.x < 64) {
    // ================= layer 0 =================
    const int rr = blockIdx.x, c0 = rr << 4;
    const float* Wsel = (g == 0) ? W0i : (g == 1) ? W0f : (g == 2) ? W0g : W0o;
    short8 wfrag[16];
#pragma unroll
    for (int kk = 0; kk < 16; ++kk)
#pragma unroll
      for (int j = 0; j < 8; ++j)
        wfrag[kk][j] = (short)f2bfbits(
            Wsel[(size_t)(512 + kh * 512 + kk * 32 + q * 8 + j) * 1024 + c0 + n]);

    float Creg = 0.f;
    const float* xpb = xp + ((size_t)g << 10) + c0 + n;
    f32x4 xpn = {0.f, 0.f, 0.f, 0.f};
    if (kh == 0) {
#pragma unroll
      for (int r = 0; r < 4; ++r)
        xpn[r] = xpb[((size_t)((q * 4 + r) * SLEN)) << 12];
    }

    for (int t = 0; t < SLEN; ++t) {
      f32x4 acc = (kh == 0) ? xpn : f32x4{0.f, 0.f, 0.f, 0.f};
      f32x4 acc2 = {0.f, 0.f, 0.f, 0.f};
      if (kh == 0 && t + 1 < SLEN) {   // prefetch before compute (flies under MFMAs)
#pragma unroll
        for (int r = 0; r < 4; ++r)
          xpn[r] = xpb[((size_t)((q * 4 + r) * SLEN + t + 1)) << 12];
      }
      if (t > 0) {
        const short* hrow = h0b16 + (((size_t)(t - 1)) << 14) + n * 1024 + kh * 512 + q * 8;
#pragma unroll
        for (int kk = 0; kk < 16; kk += 2) {
          short8 a0 = *(const short8*)(hrow + kk * 32);
          short8 a1 = *(const short8*)(hrow + kk * 32 + 32);
          acc  = __builtin_amdgcn_mfma_f32_16x16x32_bf16(a0, wfrag[kk],     acc,  0, 0, 0);
          acc2 = __builtin_amdgcn_mfma_f32_16x16x32_bf16(a1, wfrag[kk + 1], acc2, 0, 0, 0);
        }
#pragma unroll
        for (int r = 0; r < 4; ++r) acc[r] += acc2[r];
      }
#pragma unroll
      for (int r = 0; r < 4; ++r) Pre[wv][q * 4 + r][n] = acc[r];
      __syncthreads();

      if (tid < 256) {
        float pI = Pre[0][cb][cc] + Pre[4][cb][cc];
        float pF = Pre[1][cb][cc] + Pre[5][cb][cc];
        float pG = Pre[2][cb][cc] + Pre[6][cb][cc];
        float pO = Pre[3][cb][cc] + Pre[7][cb][cc];
        float gI = 1.f / (1.f + __expf(-pI));
        float gF = 1.f / (1.f + __expf(-pF));
        float gG = tanhf(pG);
        float gO = 1.f / (1.f + __expf(-pO));
        Creg = gF * Creg + gI * gG;
        float h = gO * tanhf(Creg);

        unsigned mybits = (unsigned)f2bfbits(h);
        unsigned nbbits = (unsigned)__shfl_xor((int)mybits, 1, 64);
        if ((cc & 1) == 0) {
          unsigned pk = mybits | (nbbits << 16);
          st_ag((unsigned*)(h0b16 + (((size_t)(t * 16 + cb)) << 10) + c0 + cc), pk);
        }
      }
      __syncthreads();  // implicit vmcnt(0): h stores at coherence point

      if (tid == 0) {
        st_ag(&f0a[rr], (unsigned)(t + 1));
        st_ag(&f0b[rr], (unsigned)(t + 1));
      }
      if (t + 1 < SLEN) {
        if (tid < 64) {
          const unsigned tgt = (unsigned)(t + 1);
          for (;;) {
            unsigned v0 = ld_ag(&f0a[tid]);
            if (__all((int)(v0 >= tgt))) break;
            __builtin_amdgcn_s_sleep(1);
          }
        }
        __syncthreads();
      }
    }
  } else {
    // ================= layer 1 =================
    const int rr = blockIdx.x - 64, c0 = rr << 4;
    const float* Wsel = (g == 0) ? W1i : (g == 1) ? W1f : (g == 2) ? W1g : W1o;
    const float* bsel = (g == 0) ? b1i : (g == 1) ? b1f : (g == 2) ? b1g : b1o;
    short8 wfrag[32];  // rows kh*1024 + .. (kh=0: h0-input, kh=1: h1-recurrent)
#pragma unroll
    for (int kk = 0; kk < 32; ++kk)
#pragma unroll
      for (int j = 0; j < 8; ++j)
        wfrag[kk][j] = (short)f2bfbits(
            Wsel[(size_t)(kh * 1024 + kk * 32 + q * 8 + j) * 1024 + c0 + n]);
    const float bcol = (kh == 0) ? bsel[c0 + n] : 0.f;
    const float wfc0 = Wfc[(c0 + cc) * 2 + 0];
    const float wfc1 = Wfc[(c0 + cc) * 2 + 1];
    float Creg = 0.f;

    for (int t = 0; t < SLEN; ++t) {
      // per-wave dependency polls (split: kh=0 waits h0(t), kh=1 waits h1(t-1))
      if (kh == 0) {
        const unsigned tgt0 = (unsigned)(t + 1);
        for (;;) {
          unsigned v0 = ld_ag(&f0b[lane]);
          if (__all((int)(v0 >= tgt0))) break;
          __builtin_amdgcn_s_sleep(1);
        }
      } else if (t > 0) {
        const unsigned tgt1 = (unsigned)t;
        for (;;) {
          unsigned v1 = ld_ag(&f1[lane]);
          if (__all((int)(v1 >= tgt1))) break;
          __builtin_amdgcn_s_sleep(1);
        }
      }

      f32x4 acc, acc2 = {0.f, 0.f, 0.f, 0.f};
#pragma unroll
      for (int r = 0; r < 4; ++r) acc[r] = bcol;

      if (kh == 0) {
        // A = h0(t)
        const short* xrow = h0b16 + (((size_t)t) << 14) + n * 1024 + q * 8;
#pragma unroll
        for (int kk = 0; kk < 32; kk += 2) {
          short8 a0 = *(const short8*)(xrow + kk * 32);
          short8 a1 = *(const short8*)(xrow + kk * 32 + 32);
          acc  = __builtin_amdgcn_mfma_f32_16x16x32_bf16(a0, wfrag[kk],     acc,  0, 0, 0);
          acc2 = __builtin_amdgcn_mfma_f32_16x16x32_bf16(a1, wfrag[kk + 1], acc2, 0, 0, 0);
        }
      } else if (t > 0) {
        // A = h1(t-1)
        const short* hrow = h1b16 + (((size_t)(t - 1)) << 14) + n * 1024 + q * 8;
#pragma unroll
        for (int kk = 0; kk < 32; kk += 2) {
          short8 a0 = *(const short8*)(hrow + kk * 32);
          short8 a1 = *(const short8*)(hrow + kk * 32 + 32);
          acc  = __builtin_amdgcn_mfma_f32_16x16x32_bf16(a0, wfrag[kk],     acc,  0, 0, 0);
          acc2 = __builtin_amdgcn_mfma_f32_16x16x32_bf16(a1, wfrag[kk + 1], acc2, 0, 0, 0);
        }
      }
#pragma unroll
      for (int r = 0; r < 4; ++r) acc[r] += acc2[r];

#pragma unroll
      for (int r = 0; r < 4; ++r) Pre[wv][q * 4 + r][n] = acc[r];
      __syncthreads();

      if (tid < 256) {
        float pI = Pre[0][cb][cc] + Pre[4][cb][cc];
        float pF = Pre[1][cb][cc] + Pre[5][cb][cc];
        float pG = Pre[2][cb][cc] + Pre[6][cb][cc];
        float pO = Pre[3][cb][cc] + Pre[7][cb][cc];
        float gI = 1.f / (1.f + __expf(-pI));
        float gF = 1.f / (1.f + __expf(-pF));
        float gG = tanhf(pG);
        float gO = 1.f / (1.f + __expf(-pO));
        Creg = gF * Creg + gI * gG;
        float h = gO * tanhf(Creg);

        float p0 = h * wfc0, p1 = h * wfc1;   // head partial over 16 cols
#pragma unroll
        for (int m = 1; m < 16; m <<= 1) {
          p0 += __shfl_xor(p0, m, 64);
          p1 += __shfl_xor(p1, m, 64);
        }
        if (cc == 0)
          part[(size_t)(cb * SLEN + t) * 64 + rr] = make_float2(p0, p1);

        unsigned mybits = (unsigned)f2bfbits(h);
        unsigned nbbits = (unsigned)__shfl_xor((int)mybits, 1, 64);
        if ((cc & 1) == 0) {
          unsigned pk = mybits | (nbbits << 16);
          st_ag((unsigned*)(h1b16 + (((size_t)(t * 16 + cb)) << 10) + c0 + cc), pk);
        }
      }
      __syncthreads();  // drains h1 stores

      if (tid == 0)
        st_ag(&f1[rr], (unsigned)(t + 1));
    }
  }
}

// ---------------- finalize: 64-way partial sum + bias + log_softmax ----------------
__global__ __launch_bounds__(256) void finalize_kernel(const float2* __restrict__ part,
                                                       const float* __restrict__ bfc,
                                                       float* __restrict__ out)
{
  const int lane = threadIdx.x & 63;
  const int row = blockIdx.x * 4 + (threadIdx.x >> 6);
  float2 v = part[(size_t)row * 64 + lane];
  float s0 = v.x, s1 = v.y;
#pragma unroll
  for (int off = 32; off > 0; off >>= 1) {
    s0 += __shfl_down(s0, off);
    s1 += __shfl_down(s1, off);
  }
  if (lane == 0) {
    s0 += bfc[0];
    s1 += bfc[1];
    float m = fmaxf(s0, s1);
    float lse = m + logf(expf(s0 - m) + expf(s1 - m));
    out[((size_t)row << 1) + 0] = s0 - lse;
    out[((size_t)row << 1) + 1] = s1 - lse;
  }
}

extern "C" void kernel_launch(void* const* d_in, const int* in_sizes, int n_in,
                              void* d_out, int out_size, void* d_ws, size_t ws_size,
                              hipStream_t stream)
{
  const int*   tokens = (const int*)d_in[0];
  const float* emb = (const float*)d_in[1];
  const float* W0i = (const float*)d_in[2];
  const float* b0i = (const float*)d_in[3];
  const float* W0f = (const float*)d_in[4];
  const float* b0f = (const float*)d_in[5];
  const float* W0g = (const float*)d_in[6];
  const float* b0g = (const float*)d_in[7];
  const float* W0o = (const float*)d_in[8];
  const float* b0o = (const float*)d_in[9];
  const float* W1i = (const float*)d_in[10];
  const float* b1i = (const float*)d_in[11];
  const float* W1f = (const float*)d_in[12];
  const float* b1f = (const float*)d_in[13];
  const float* W1g = (const float*)d_in[14];
  const float* b1g = (const float*)d_in[15];
  const float* W1o = (const float*)d_in[16];
  const float* b1o = (const float*)d_in[17];
  const float* Wfc = (const float*)d_in[18];
  const float* bfc = (const float*)d_in[19];
  float* out = (float*)d_out;

  float* ws = (float*)d_ws;
  float* x0 = ws;                               // 16MB region: x0bf (8MB) then h0 bf16 (16MB)
  float* hA = x0 + (size_t)8192 * 512;          // 32MB: h1 (16MB) + part (4MB) + Wt (4MB in spare)
  float* xp = hA + (size_t)8192 * 1024;         // 128MB layer-0 x-preacts (f32)
  unsigned* ctl = (unsigned*)(xp + (size_t)8192 * 4096);  // 256 u32 (proven offset)

  short*  x0bf = (short*)x0;                    // bf16 [8192][512]
  short*  h0   = (short*)x0;                    // bf16 [t][b][1024] (after xproj)
  short*  h1   = (short*)hA;                    // bf16 [t][b][1024]
  float2* part = (float2*)(hA + (size_t)8192 * 512);            // 16..20MB of hA
  short*  Wt   = (short*)(hA + (size_t)5 * 1024 * 1024);        // 20..24MB of hA

  zero_cnt_kernel<<<1, 256, 0, stream>>>(ctl);
  embed_bf16_kernel<<<2048, 256, 0, stream>>>(tokens, emb, x0bf);
  wconv_kernel<<<1024, 256, 0, stream>>>(W0i, W0f, W0g, W0o, Wt);
  xproj_mfma_kernel<<<dim3(64, 512), 256, 0, stream>>>(x0bf, Wt,
                                                       b0i, b0f, b0g, b0o, xp);
  lstm_pipe<<<128, 512, 0, stream>>>(xp,
                                     W0i, W0f, W0g, W0o,
                                     W1i, W1f, W1g, W1o,
                                     b1i, b1f, b1g, b1o,
                                     Wfc, h0, h1, part, ctl);
  finalize_kernel<<<2048, 256, 0, stream>>>(part, bfc, out);
}

// Round 9
// 5564.589 us; speedup vs baseline: 2.0077x; 1.0110x over previous
//
#include <hip/hip_runtime.h>
#include <math.h>

// MultilayerLSTM: B=16, S=512, D_IN=512, D_H=1024, D_OUT=2, VOCAB=32000
// Round 11: poll decongestion (round-10 retry; fixed s_sleep constant-arg).
// Round-7 FETCH=375MB vs ~50MB real data => ~325MB/dispatch of agent-scope
// flag-poll loads (bypass L2, hit MALL) from ~37k polling lanes -> MALL
// saturated -> every data/flag hop queued behind poll traffic. Changes vs
// the verified 5626us kernel:
//   - poll_flags64<SLP>: 16 lanes x dwordx4 (4 flags/lane, min-reduce)
//     instead of 64 lanes x dword -> 4x fewer requests per poll iteration.
//   - l1: only wave g==0 of each K-half polls MALL; waves g=1..3 spin on an
//     LDS ready word (zero fabric traffic). Poller lanes 36864 -> 3072.
//   - s_sleep 2 in MALL polls (template constant).
// Everything else (MFMA xproj, frag layout, flag protocol, footprint) is
// identical to the 5626us verified kernel.

#define SLEN  512

#define C_F0A  64
#define C_F0B  128
#define C_F1   192

typedef __attribute__((ext_vector_type(8))) short short8;
typedef __attribute__((ext_vector_type(4))) float f32x4;
typedef __attribute__((ext_vector_type(4))) unsigned u32x4;

__device__ inline unsigned short f2bfbits(float x) {
  union { float f; unsigned u; } v; v.f = x;
  unsigned r = v.u + 0x7FFF + ((v.u >> 16) & 1);  // RNE
  return (unsigned short)(r >> 16);
}

__device__ inline unsigned ld_ag(const unsigned* p) {
  return __hip_atomic_load(p, __ATOMIC_RELAXED, __HIP_MEMORY_SCOPE_AGENT);
}
__device__ inline void st_ag(unsigned* p, unsigned v) {
  __hip_atomic_store(p, v, __ATOMIC_RELAXED, __HIP_MEMORY_SCOPE_AGENT);
}

// 16B cache-bypassing load (agent-fresh), for flag polling
__device__ inline u32x4 ld_ag4(const unsigned* p) {
  u32x4 v;
  asm volatile("global_load_dwordx4 %0, %1, off sc0 sc1\n\ts_waitcnt vmcnt(0)"
               : "=v"(v) : "v"(p) : "memory");
  return v;
}

// one wave polls 64 flags: lanes 0..15 load 4 flags each, min-reduce, __all
template <int SLP>
__device__ inline void poll_flags64(const unsigned* f, unsigned tgt, int lane) {
  for (;;) {
    int ok = 1;
    if (lane < 16) {
      u32x4 v = ld_ag4(f + (lane << 2));
      unsigned a = v[0] < v[1] ? v[0] : v[1];
      unsigned b = v[2] < v[3] ? v[2] : v[3];
      ok = ((a < b ? a : b) >= tgt);
    }
    if (__all(ok)) break;
    __builtin_amdgcn_s_sleep(SLP);
  }
  asm volatile("" ::: "memory");
}

// ---------------- zero flags ----------------
__global__ void zero_cnt_kernel(unsigned* cnt) {
  cnt[threadIdx.x] = 0;   // launched with 256 threads
}

// ---------------- embedding gather -> bf16 x0 ----------------
__global__ __launch_bounds__(256) void embed_bf16_kernel(const int* __restrict__ tokens,
                                                         const float* __restrict__ emb,
                                                         short* __restrict__ x0bf) {
  int idx = blockIdx.x * 256 + threadIdx.x;   // over 8192 * 64 chunks of 8
  int r = idx >> 6, c8 = (idx & 63) << 3;
  int tok = tokens[r];
  const float* src = emb + ((size_t)tok << 9) + c8;
  float4 a = *(const float4*)(src);
  float4 b = *(const float4*)(src + 4);
  short8 o;
  o[0] = (short)f2bfbits(a.x); o[1] = (short)f2bfbits(a.y);
  o[2] = (short)f2bfbits(a.z); o[3] = (short)f2bfbits(a.w);
  o[4] = (short)f2bfbits(b.x); o[5] = (short)f2bfbits(b.y);
  o[6] = (short)f2bfbits(b.z); o[7] = (short)f2bfbits(b.w);
  *(short8*)(x0bf + ((size_t)r << 9) + c8) = o;
}

// ---------------- W0 input rows -> transposed bf16 Wt[gate*1024+col][512] ----------------
__global__ __launch_bounds__(256) void wconv_kernel(const float* __restrict__ Wi,
                                                    const float* __restrict__ Wf,
                                                    const float* __restrict__ Wg,
                                                    const float* __restrict__ Wo,
                                                    short* __restrict__ Wt) {
  int gid = blockIdx.x * 256 + threadIdx.x;   // 4 * 1024 * 64
  int gi = gid >> 16;
  int rem = gid & 65535;
  int col = rem >> 6;
  int k8 = (rem & 63) << 3;
  const float* W = (gi == 0) ? Wi : (gi == 1) ? Wf : (gi == 2) ? Wg : Wo;
  short8 o;
#pragma unroll
  for (int j = 0; j < 8; ++j)
    o[j] = (short)f2bfbits(W[(size_t)(k8 + j) * 1024 + col]);
  *(short8*)(Wt + (((size_t)((gi << 10) + col)) << 9) + k8) = o;
}

// ---------------- xproj via MFMA: xp[m][4096] = x0bf[m][512] @ W + b ----------------
__global__ __launch_bounds__(256) void xproj_mfma_kernel(
    const short* __restrict__ x0bf,
    const short* __restrict__ Wt,
    const float* __restrict__ bi, const float* __restrict__ bf,
    const float* __restrict__ bg, const float* __restrict__ bo,
    float* __restrict__ xp)
{
  const int tid = threadIdx.x;
  const int w = tid >> 6;
  const int lane = tid & 63;
  const int q = lane >> 4;
  const int n = lane & 15;
  const int cx = blockIdx.x;
  const int g = cx >> 4;
  const int cbase = ((cx & 15) << 6) + (w << 4);   // col within gate
  const int m0 = blockIdx.y << 4;
  const float* bias = (g == 0) ? bi : (g == 1) ? bf : (g == 2) ? bg : bo;

  const short* wp = Wt + (((size_t)((g << 10) + cbase + n)) << 9) + q * 8;
  short8 wfrag[16];
#pragma unroll
  for (int kk = 0; kk < 16; ++kk) wfrag[kk] = *(const short8*)(wp + kk * 32);

  const float bcol = bias[cbase + n];
  f32x4 acc, acc2 = {0.f, 0.f, 0.f, 0.f};
#pragma unroll
  for (int r = 0; r < 4; ++r) acc[r] = bcol;

  const short* ap = x0bf + (((size_t)(m0 + n)) << 9) + q * 8;
#pragma unroll
  for (int kk = 0; kk < 16; kk += 2) {
    short8 a0 = *(const short8*)(ap + kk * 32);
    short8 a1 = *(const short8*)(ap + kk * 32 + 32);
    acc  = __builtin_amdgcn_mfma_f32_16x16x32_bf16(a0, wfrag[kk],     acc,  0, 0, 0);
    acc2 = __builtin_amdgcn_mfma_f32_16x16x32_bf16(a1, wfrag[kk + 1], acc2, 0, 0, 0);
  }
#pragma unroll
  for (int r = 0; r < 4; ++r) acc[r] += acc2[r];

#pragma unroll
  for (int r = 0; r < 4; ++r)
    xp[(((size_t)(m0 + q * 4 + r)) << 12) + (g << 10) + cbase + n] = acc[r];
}

// ---------------- fused pipelined 2-layer LSTM recurrence ----------------
// 128 blocks x 512 threads (8 waves). blk 0..63: layer 0 cols blk*16
// (wave = gate x K-half). blk 64..127: layer 1 cols (blk-64)*16
// (wave kh=0: h0(t)-input K=1024; kh=1: h1(t-1)-recurrent K=1024).
__global__ __launch_bounds__(512, 2) void lstm_pipe(
    const float* __restrict__ xp,
    const float* __restrict__ W0i, const float* __restrict__ W0f,
    const float* __restrict__ W0g, const float* __restrict__ W0o,
    const float* __restrict__ W1i, const float* __restrict__ W1f,
    const float* __restrict__ W1g, const float* __restrict__ W1o,
    const float* __restrict__ b1i, const float* __restrict__ b1f,
    const float* __restrict__ b1g, const float* __restrict__ b1o,
    const float* __restrict__ Wfc,
    short* __restrict__ h0b16,
    short* __restrict__ h1b16,
    float2* __restrict__ part,
    unsigned* __restrict__ ctl)
{
  __shared__ float Pre[8][16][17];
  __shared__ unsigned rdy0, rdy1;
  const int tid  = threadIdx.x;
  const int wv   = tid >> 6;         // 0..7
  const int g    = wv & 3;           // gate
  const int kh   = wv >> 2;          // K-half
  const int lane = tid & 63;
  const int q    = lane >> 4;
  const int n    = lane & 15;
  const int cb   = tid >> 4, cc = tid & 15;  // cell mapping (tid<256)

  unsigned* f0a = ctl + C_F0A;
  unsigned* f0b = ctl + C_F0B;
  unsigned* f1  = ctl + C_F1;

  if (blockIdx.x < 64) {
    // ================= layer 0 =================
    const int rr = blockIdx.x, c0 = rr << 4;
    const float* Wsel = (g == 0) ? W0i : (g == 1) ? W0f : (g == 2) ? W0g : W0o;
    short8 wfrag[16];
#pragma unroll
    for (int kk = 0; kk < 16; ++kk)
#pragma unroll
      for (int j = 0; j < 8; ++j)
        wfrag[kk][j] = (short)f2bfbits(
            Wsel[(size_t)(512 + kh * 512 + kk * 32 + q * 8 + j) * 1024 + c0 + n]);

    float Creg = 0.f;
    const float* xpb = xp + ((size_t)g << 10) + c0 + n;
    f32x4 xpn = {0.f, 0.f, 0.f, 0.f};
    if (kh == 0) {
#pragma unroll
      for (int r = 0; r < 4; ++r)
        xpn[r] = xpb[((size_t)((q * 4 + r) * SLEN)) << 12];
    }

    for (int t = 0; t < SLEN; ++t) {
      f32x4 acc = (kh == 0) ? xpn : f32x4{0.f, 0.f, 0.f, 0.f};
      f32x4 acc2 = {0.f, 0.f, 0.f, 0.f};
      if (kh == 0 && t + 1 < SLEN) {   // prefetch before compute (flies under MFMAs)
#pragma unroll
        for (int r = 0; r < 4; ++r)
          xpn[r] = xpb[((size_t)((q * 4 + r) * SLEN + t + 1)) << 12];
      }
      if (t > 0) {
        const short* hrow = h0b16 + (((size_t)(t - 1)) << 14) + n * 1024 + kh * 512 + q * 8;
#pragma unroll
        for (int kk = 0; kk < 16; kk += 2) {
          short8 a0 = *(const short8*)(hrow + kk * 32);
          short8 a1 = *(const short8*)(hrow + kk * 32 + 32);
          acc  = __builtin_amdgcn_mfma_f32_16x16x32_bf16(a0, wfrag[kk],     acc,  0, 0, 0);
          acc2 = __builtin_amdgcn_mfma_f32_16x16x32_bf16(a1, wfrag[kk + 1], acc2, 0, 0, 0);
        }
#pragma unroll
        for (int r = 0; r < 4; ++r) acc[r] += acc2[r];
      }
#pragma unroll
      for (int r = 0; r < 4; ++r) Pre[wv][q * 4 + r][n] = acc[r];
      __syncthreads();

      if (tid < 256) {
        float pI = Pre[0][cb][cc] + Pre[4][cb][cc];
        float pF = Pre[1][cb][cc] + Pre[5][cb][cc];
        float pG = Pre[2][cb][cc] + Pre[6][cb][cc];
        float pO = Pre[3][cb][cc] + Pre[7][cb][cc];
        float gI = 1.f / (1.f + __expf(-pI));
        float gF = 1.f / (1.f + __expf(-pF));
        float gG = tanhf(pG);
        float gO = 1.f / (1.f + __expf(-pO));
        Creg = gF * Creg + gI * gG;
        float h = gO * tanhf(Creg);

        unsigned mybits = (unsigned)f2bfbits(h);
        unsigned nbbits = (unsigned)__shfl_xor((int)mybits, 1, 64);
        if ((cc & 1) == 0) {
          unsigned pk = mybits | (nbbits << 16);
          st_ag((unsigned*)(h0b16 + (((size_t)(t * 16 + cb)) << 10) + c0 + cc), pk);
        }
      }
      __syncthreads();  // implicit vmcnt(0): h stores at coherence point

      if (tid == 0) {
        st_ag(&f0a[rr], (unsigned)(t + 1));
        st_ag(&f0b[rr], (unsigned)(t + 1));
      }
      if (t + 1 < SLEN) {
        if (tid < 64) poll_flags64<2>(f0a, (unsigned)(t + 1), lane);
        __syncthreads();
      }
    }
  } else {
    // ================= layer 1 =================
    const int rr = blockIdx.x - 64, c0 = rr << 4;
    const float* Wsel = (g == 0) ? W1i : (g == 1) ? W1f : (g == 2) ? W1g : W1o;
    const float* bsel = (g == 0) ? b1i : (g == 1) ? b1f : (g == 2) ? b1g : b1o;
    short8 wfrag[32];  // rows kh*1024 + .. (kh=0: h0-input, kh=1: h1-recurrent)
#pragma unroll
    for (int kk = 0; kk < 32; ++kk)
#pragma unroll
      for (int j = 0; j < 8; ++j)
        wfrag[kk][j] = (short)f2bfbits(
            Wsel[(size_t)(kh * 1024 + kk * 32 + q * 8 + j) * 1024 + c0 + n]);
    const float bcol = (kh == 0) ? bsel[c0 + n] : 0.f;
    const float wfc0 = Wfc[(c0 + cc) * 2 + 0];
    const float wfc1 = Wfc[(c0 + cc) * 2 + 1];
    float Creg = 0.f;

    if (tid == 0) { rdy0 = 0u; rdy1 = 0u; }
    __syncthreads();

    for (int t = 0; t < SLEN; ++t) {
      // dependency waits: wave g==0 of each K-half polls MALL; g>0 spin on LDS
      if (kh == 0) {
        const unsigned tgt0 = (unsigned)(t + 1);
        if (g == 0) {
          poll_flags64<2>(f0b, tgt0, lane);
          __hip_atomic_store(&rdy0, tgt0, __ATOMIC_RELAXED, __HIP_MEMORY_SCOPE_WORKGROUP);
        } else {
          while (__hip_atomic_load(&rdy0, __ATOMIC_RELAXED, __HIP_MEMORY_SCOPE_WORKGROUP) < tgt0)
            __builtin_amdgcn_s_sleep(1);
          asm volatile("" ::: "memory");
        }
      } else if (t > 0) {
        const unsigned tgt1 = (unsigned)t;
        if (g == 0) {
          poll_flags64<2>(f1, tgt1, lane);
          __hip_atomic_store(&rdy1, tgt1, __ATOMIC_RELAXED, __HIP_MEMORY_SCOPE_WORKGROUP);
        } else {
          while (__hip_atomic_load(&rdy1, __ATOMIC_RELAXED, __HIP_MEMORY_SCOPE_WORKGROUP) < tgt1)
            __builtin_amdgcn_s_sleep(1);
          asm volatile("" ::: "memory");
        }
      }

      f32x4 acc, acc2 = {0.f, 0.f, 0.f, 0.f};
#pragma unroll
      for (int r = 0; r < 4; ++r) acc[r] = bcol;

      if (kh == 0) {
        // A = h0(t)
        const short* xrow = h0b16 + (((size_t)t) << 14) + n * 1024 + q * 8;
#pragma unroll
        for (int kk = 0; kk < 32; kk += 2) {
          short8 a0 = *(const short8*)(xrow + kk * 32);
          short8 a1 = *(const short8*)(xrow + kk * 32 + 32);
          acc  = __builtin_amdgcn_mfma_f32_16x16x32_bf16(a0, wfrag[kk],     acc,  0, 0, 0);
          acc2 = __builtin_amdgcn_mfma_f32_16x16x32_bf16(a1, wfrag[kk + 1], acc2, 0, 0, 0);
        }
      } else if (t > 0) {
        // A = h1(t-1)
        const short* hrow = h1b16 + (((size_t)(t - 1)) << 14) + n * 1024 + q * 8;
#pragma unroll
        for (int kk = 0; kk < 32; kk += 2) {
          short8 a0 = *(const short8*)(hrow + kk * 32);
          short8 a1 = *(const short8*)(hrow + kk * 32 + 32);
          acc  = __builtin_amdgcn_mfma_f32_16x16x32_bf16(a0, wfrag[kk],     acc,  0, 0, 0);
          acc2 = __builtin_amdgcn_mfma_f32_16x16x32_bf16(a1, wfrag[kk + 1], acc2, 0, 0, 0);
        }
      }
#pragma unroll
      for (int r = 0; r < 4; ++r) acc[r] += acc2[r];

#pragma unroll
      for (int r = 0; r < 4; ++r) Pre[wv][q * 4 + r][n] = acc[r];
      __syncthreads();

      if (tid < 256) {
        float pI = Pre[0][cb][cc] + Pre[4][cb][cc];
        float pF = Pre[1][cb][cc] + Pre[5][cb][cc];
        float pG = Pre[2][cb][cc] + Pre[6][cb][cc];
        float pO = Pre[3][cb][cc] + Pre[7][cb][cc];
        float gI = 1.f / (1.f + __expf(-pI));
        float gF = 1.f / (1.f + __expf(-pF));
        float gG = tanhf(pG);
        float gO = 1.f / (1.f + __expf(-pO));
        Creg = gF * Creg + gI * gG;
        float h = gO * tanhf(Creg);

        float p0 = h * wfc0, p1 = h * wfc1;   // head partial over 16 cols
#pragma unroll
        for (int m = 1; m < 16; m <<= 1) {
          p0 += __shfl_xor(p0, m, 64);
          p1 += __shfl_xor(p1, m, 64);
        }
        if (cc == 0)
          part[(size_t)(cb * SLEN + t) * 64 + rr] = make_float2(p0, p1);

        unsigned mybits = (unsigned)f2bfbits(h);
        unsigned nbbits = (unsigned)__shfl_xor((int)mybits, 1, 64);
        if ((cc & 1) == 0) {
          unsigned pk = mybits | (nbbits << 16);
          st_ag((unsigned*)(h1b16 + (((size_t)(t * 16 + cb)) << 10) + c0 + cc), pk);
        }
      }
      __syncthreads();  // drains h1 stores

      if (tid == 0)
        st_ag(&f1[rr], (unsigned)(t + 1));
    }
  }
}

// ---------------- finalize: 64-way partial sum + bias + log_softmax ----------------
__global__ __launch_bounds__(256) void finalize_kernel(const float2* __restrict__ part,
                                                       const float* __restrict__ bfc,
                                                       float* __restrict__ out)
{
  const int lane = threadIdx.x & 63;
  const int row = blockIdx.x * 4 + (threadIdx.x >> 6);
  float2 v = part[(size_t)row * 64 + lane];
  float s0 = v.x, s1 = v.y;
#pragma unroll
  for (int off = 32; off > 0; off >>= 1) {
    s0 += __shfl_down(s0, off);
    s1 += __shfl_down(s1, off);
  }
  if (lane == 0) {
    s0 += bfc[0];
    s1 += bfc[1];
    float m = fmaxf(s0, s1);
    float lse = m + logf(expf(s0 - m) + expf(s1 - m));
    out[((size_t)row << 1) + 0] = s0 - lse;
    out[((size_t)row << 1) + 1] = s1 - lse;
  }
}

extern "C" void kernel_launch(void* const* d_in, const int* in_sizes, int n_in,
                              void* d_out, int out_size, void* d_ws, size_t ws_size,
                              hipStream_t stream)
{
  const int*   tokens = (const int*)d_in[0];
  const float* emb = (const float*)d_in[1];
  const float* W0i = (const float*)d_in[2];
  const float* b0i = (const float*)d_in[3];
  const float* W0f = (const float*)d_in[4];
  const float* b0f = (const float*)d_in[5];
  const float* W0g = (const float*)d_in[6];
  const float* b0g = (const float*)d_in[7];
  const float* W0o = (const float*)d_in[8];
  const float* b0o = (const float*)d_in[9];
  const float* W1i = (const float*)d_in[10];
  const float* b1i = (const float*)d_in[11];
  const float* W1f = (const float*)d_in[12];
  const float* b1f = (const float*)d_in[13];
  const float* W1g = (const float*)d_in[14];
  const float* b1g = (const float*)d_in[15];
  const float* W1o = (const float*)d_in[16];
  const float* b1o = (const float*)d_in[17];
  const float* Wfc = (const float*)d_in[18];
  const float* bfc = (const float*)d_in[19];
  float* out = (float*)d_out;

  float* ws = (float*)d_ws;
  float* x0 = ws;                               // 16MB region: x0bf (8MB) then h0 bf16 (16MB)
  float* hA = x0 + (size_t)8192 * 512;          // 32MB: h1 (16MB) + part (4MB) + Wt (4MB in spare)
  float* xp = hA + (size_t)8192 * 1024;         // 128MB layer-0 x-preacts (f32)
  unsigned* ctl = (unsigned*)(xp + (size_t)8192 * 4096);  // 256 u32 (proven offset)

  short*  x0bf = (short*)x0;                    // bf16 [8192][512]
  short*  h0   = (short*)x0;                    // bf16 [t][b][1024] (after xproj)
  short*  h1   = (short*)hA;                    // bf16 [t][b][1024]
  float2* part = (float2*)(hA + (size_t)8192 * 512);            // 16..20MB of hA
  short*  Wt   = (short*)(hA + (size_t)5 * 1024 * 1024);        // 20..24MB of hA

  zero_cnt_kernel<<<1, 256, 0, stream>>>(ctl);
  embed_bf16_kernel<<<2048, 256, 0, stream>>>(tokens, emb, x0bf);
  wconv_kernel<<<1024, 256, 0, stream>>>(W0i, W0f, W0g, W0o, Wt);
  xproj_mfma_kernel<<<dim3(64, 512), 256, 0, stream>>>(x0bf, Wt,
                                                       b0i, b0f, b0g, b0o, xp);
  lstm_pipe<<<128, 512, 0, stream>>>(xp,
                                     W0i, W0f, W0g, W0o,
                                     W1i, W1f, W1g, W1o,
                                     b1i, b1f, b1g, b1o,
                                     Wfc, h0, h1, part, ctl);
  finalize_kernel<<<2048, 256, 0, stream>>>(part, bfc, out);
}